// Round 8
// baseline (295.609 us; speedup 1.0000x reference)
//
#include <hip/hip_runtime.h>
#include <hip/hip_bf16.h>
#include <stdint.h>
#include <stddef.h>

#define B_ 8
#define S_ 2048
#define E_ 1024
#define H_ 128
#define NR_ (B_ * S_)   // 16384 total q-rows

typedef __attribute__((ext_vector_type(8)))  short short8;   // 8 x bf16
typedef __attribute__((ext_vector_type(4)))  short short4v;
typedef __attribute__((ext_vector_type(4)))  float f32x4;
typedef __attribute__((ext_vector_type(16))) float f32x16;   // 32x32 MFMA acc

__device__ __forceinline__ short f2bf(float f){
  uint32_t u = __builtin_bit_cast(uint32_t, f);
  u = (u + 0x7FFFu + ((u >> 16) & 1u)) >> 16;   // RNE
  return (short)(uint16_t)u;
}

#define GLOBAL_AS __attribute__((address_space(1)))
#define LDS_AS    __attribute__((address_space(3)))
__device__ __forceinline__ void async16(const void* g, void* l){
  __builtin_amdgcn_global_load_lds((const GLOBAL_AS uint32_t*)g,
                                   (LDS_AS uint32_t*)l, 16, 0, 0);
}

// ---------------------------------------------------------------------------
// prep = cast_x (blocks 0..8191) + pack_w (blocks 8192..8575).
// ---------------------------------------------------------------------------
__global__ void prep(const float* __restrict__ x, const float* __restrict__ wq,
                     const float* __restrict__ wk, const float* __restrict__ wv,
                     short* __restrict__ xb, short* __restrict__ wt){
  __shared__ float t[32][33];
  int bid = blockIdx.x;
  if (bid < 8192){
    size_t i = ((size_t)bid * 256 + threadIdx.x) * 8;
    f32x4 a = *(const f32x4*)(x + i);
    f32x4 b = *(const f32x4*)(x + i + 4);
    short8 o;
#pragma unroll
    for (int j = 0; j < 4; j++){ o[j] = f2bf(a[j]); o[j + 4] = f2bf(b[j]); }
    *(short8*)(xb + i) = o;
  } else {
    int idx = bid - 8192;
    int hb  = idx & 3;
    int eb  = (idx >> 2) & 31;
    int w   = idx >> 7;
    const float* src = (w == 0) ? wq : (w == 1) ? wk : wv;
    int c  = threadIdx.x & 31;
    int r0 = threadIdx.x >> 5;
#pragma unroll
    for (int i = 0; i < 4; i++){
      int r = r0 * 4 + i;
      t[r][c] = src[(size_t)(eb * 32 + r) * H_ + hb * 32 + c];
    }
    __syncthreads();
#pragma unroll
    for (int i = 0; i < 4; i++){
      int r = r0 * 4 + i;
      wt[(size_t)(w * 128 + hb * 32 + r) * E_ + eb * 32 + c] = f2bf(t[c][r]);
    }
  }
}

// ---------------------------------------------------------------------------
// QKV GEMM v6 (unchanged from R7): m97-pattern 128x128 tile, V transpose
// fused into the nb==2 epilogue.
// ---------------------------------------------------------------------------
__launch_bounds__(256)
__global__ void qkv_gemm(const short* __restrict__ xb, const short* __restrict__ wt,
                         short* __restrict__ qm, short* __restrict__ km,
                         short* __restrict__ vt){
  __shared__ __align__(16) short smem[16896];
  const int wave = threadIdx.x >> 6;
  const int lane = threadIdx.x & 63;
  const int l16  = lane & 15;
  const int quad = lane >> 4;
  const int nb   = blockIdx.x;        // 0..2  (q,k,v)
  const int m0   = blockIdx.y * 128;
  const int n0   = nb * 128;

  f32x4 acc[4][4];
#pragma unroll
  for (int i = 0; i < 4; i++)
#pragma unroll
    for (int j = 0; j < 4; j++) acc[i][j] = (f32x4)(0.0f);

#define STAGE(buf, k0)                                                        \
  {                                                                           \
    _Pragma("unroll")                                                         \
    for (int i = 0; i < 2; i++){                                              \
      int c = wave * 2 + i;                                                   \
      int r = c * 16 + (lane >> 2);                                           \
      int q = ((lane & 3) ^ ((r >> 1) & 3)) & 3;                              \
      async16(xb + (size_t)(m0 + r) * E_ + (k0) + q * 8,                      \
              (char*)(smem + (buf) * 4096) + c * 1024);                       \
      async16(wt + (size_t)(n0 + r) * E_ + (k0) + q * 8,                      \
              (char*)(smem + 8192 + (buf) * 4096) + c * 1024);                \
    }                                                                         \
  }

  STAGE(0, 0)
  for (int ks = 0; ks < 32; ks++){
    const int k0 = ks * 32;
    __syncthreads();
    if (ks < 31) STAGE((ks + 1) & 1, k0 + 32)

    const short* a = smem + (ks & 1) * 4096;
    const short* b = smem + 8192 + (ks & 1) * 4096;
    short8 af[4], bf[4];
#pragma unroll
    for (int t = 0; t < 4; t++){
      int ra = (wave & 1) * 64 + t * 16 + l16;
      int pa = (quad ^ ((ra >> 1) & 3)) & 3;
      af[t] = *(const short8*)(a + ra * 32 + pa * 8);
      int rb = (wave >> 1) * 64 + t * 16 + l16;
      int pb = (quad ^ ((rb >> 1) & 3)) & 3;
      bf[t] = *(const short8*)(b + rb * 32 + pb * 8);
    }
#pragma unroll
    for (int mt = 0; mt < 4; mt++)
#pragma unroll
      for (int nt = 0; nt < 4; nt++)
        acc[mt][nt] = __builtin_amdgcn_mfma_f32_16x16x32_bf16(af[mt], bf[nt], acc[mt][nt], 0, 0, 0);
  }
#undef STAGE

  if (nb != 2){
    short* dst = (nb == 0) ? qm : km;
#pragma unroll
    for (int mt = 0; mt < 4; mt++)
#pragma unroll
      for (int nt = 0; nt < 4; nt++){
        int row = m0 + (wave & 1) * 64 + mt * 16 + quad * 4;
        int col = (wave >> 1) * 64 + nt * 16 + l16;
#pragma unroll
        for (int r = 0; r < 4; r++)
          dst[(size_t)(row + r) * H_ + col] = f2bf(acc[mt][nt][r]);
      }
  } else {
    __syncthreads();
#pragma unroll
    for (int mt = 0; mt < 4; mt++)
#pragma unroll
      for (int nt = 0; nt < 4; nt++){
        int scol = (wave & 1) * 64 + mt * 16 + quad * 4;
        int hrow = (wave >> 1) * 64 + nt * 16 + l16;
        short4v t4;
#pragma unroll
        for (int r = 0; r < 4; r++) t4[r] = f2bf(acc[mt][nt][r]);
        *(short4v*)(smem + hrow * 132 + scol) = t4;
      }
    __syncthreads();
    int h   = threadIdx.x >> 1;
    int s0  = (threadIdx.x & 1) * 64;
    int bb_ = m0 >> 11;
    short* dstv = vt + ((size_t)bb_ * H_ + h) * S_ + (m0 & (S_ - 1)) + s0;
    const short* srcv = smem + h * 132 + s0;
#pragma unroll
    for (int i = 0; i < 8; i++)
      *(short8*)(dstv + i * 8) = *(const short8*)(srcv + i * 8);
  }
}

// ---------------------------------------------------------------------------
// Attention v6: 32x32x16 MFMA. Wave owns 32 q-rows (block 256 thr = 128 rows)
// -> QK/PV LDS fragment traffic per q-row HALVED vs 16x16 (16 KB / 32 rows).
// Layouts (m74/m101): C/D col=lane&31,row=(reg&3)+8*(reg>>2)+4*(lane>>5);
// A/B [lane&31][(lane>>5)*8+j]. pbuf [qrow][key] stride 72 shorts: b16
// C-layout writes, b128 A-layout reads (16B-aligned). K/V staged via DMA with
// the same XOR-swizzled slots as v5. No online max; per-lane l in C-layout
// regs, one 5-shuffle reduce at end. Dropout select in A-layout.
// ---------------------------------------------------------------------------
__launch_bounds__(256)
__global__ void attn(const short* __restrict__ qm, const short* __restrict__ km,
                     const short* __restrict__ vtm, const float* __restrict__ du,
                     float* __restrict__ po, float* __restrict__ pl,
                     float* __restrict__ out, int split){
  const int wave = threadIdx.x >> 6;
  const int lane = threadIdx.x & 63;
  const int l32  = lane & 31;
  const int h5   = lane >> 5;                   // half-wave index
  const int sp   = blockIdx.x & (split - 1);    // split is 1/2/4
  const int rbk  = blockIdx.x / split;
  const int b    = rbk >> 4;                    // 16 row-blocks per batch
  const int m0   = (rbk & 15) * 128 + wave * 32;
  const int seg  = S_ / split;

  const short* qb  = qm  + ((size_t)b * S_ + m0) * H_;
  const short* kb  = km  + (size_t)b * S_ * H_;
  const short* vb  = vtm + (size_t)b * H_ * S_;
  const float* dub = du  + ((size_t)b * S_ + m0) * S_;

  __shared__ __align__(16) short kls[8192];     // [64 key][128 h] swizzled
  __shared__ __align__(16) short vls[8192];     // [128 h][64 t]  swizzled
  __shared__ short pbuf[4][32][72];             // [qrow][key] bf16, per-wave
  short* pb = &pbuf[wave][0][0];

  // Q A-frags: qf[kc] = Q[m0+l32][kc*16 + h5*8 .. +8]
  short8 qf[8];
#pragma unroll
  for (int kc = 0; kc < 8; kc++)
    qf[kc] = *(const short8*)(qb + (size_t)l32 * H_ + kc * 16 + h5 * 8);

  f32x16 o[4];
#pragma unroll
  for (int ht = 0; ht < 4; ht++) o[ht] = (f32x16)(0.0f);
  float lpart[16];
#pragma unroll
  for (int r = 0; r < 16; r++) lpart[r] = 0.f;

  const float SC2  = 0.045084220f;              // log2(e) / 32
  const float KINV = 1.0f / 0.9f;

  const int tbeg = sp * seg;
  for (int t0 = tbeg; t0 < tbeg + seg; t0 += 64){
    // ---- stage K (16 chunks of 1 KB) + V (16 chunks), 4+4 per wave ----
#pragma unroll
    for (int i = 0; i < 4; i++){
      int c = wave * 4 + i;
      int r = c * 4 + (lane >> 4);
      int s = lane & 15;
      int q = (s & 8) | ((s ^ r) & 7);
      async16(kb + (size_t)(t0 + r) * H_ + q * 8, (char*)kls + c * 1024);
    }
#pragma unroll
    for (int i = 0; i < 4; i++){
      int c = wave * 4 + i;
      int r = c * 8 + (lane >> 3);
      int s = lane & 7;
      int q = (s ^ r) & 7;
      async16(vb + (size_t)r * S_ + t0 + q * 8, (char*)vls + c * 1024);
    }
    __syncthreads();

    // du for A-layout mask: row l32, keys t0 + kc*16 + h5*8 + (0..7)
    f32x4 dva[4], dvb[4];
#pragma unroll
    for (int kc = 0; kc < 4; kc++){
      const float* dp = dub + (size_t)l32 * S_ + t0 + kc * 16 + h5 * 8;
      dva[kc] = *(const f32x4*)(dp);
      dvb[kc] = *(const f32x4*)(dp + 4);
    }

    // ---- S = Q K^T, 2 nt of 32 keys, 8 kc each ----
#pragma unroll
    for (int nt = 0; nt < 2; nt++){
      f32x16 sa = (f32x16)(0.0f);
      int key = nt * 32 + l32;
#pragma unroll
      for (int kc = 0; kc < 8; kc++){
        int slot = kc * 2 + h5;                 // 0..15
        int ph   = (slot & 8) | ((slot ^ key) & 7);
        short8 bf = *(const short8*)((const char*)kls + key * 256 + ph * 16);
        sa = __builtin_amdgcn_mfma_f32_32x32x16_bf16(qf[kc], bf, sa, 0, 0, 0);
      }
#pragma unroll
      for (int r = 0; r < 16; r++){
        float p = exp2f(sa[r] * SC2);
        lpart[r] += p;
        int row = (r & 3) + 8 * (r >> 2) + 4 * h5;
        pb[row * 72 + nt * 32 + l32] = f2bf(p);
      }
    }

    __builtin_amdgcn_sched_barrier(0);
    __builtin_amdgcn_s_waitcnt(0xC07F);         // lgkmcnt(0) only
    __builtin_amdgcn_sched_barrier(0);

    // ---- P A-frags + dropout select ----
    short8 pa[4];
#pragma unroll
    for (int kc = 0; kc < 4; kc++){
      short8 pv = *(const short8*)(pb + l32 * 72 + kc * 16 + h5 * 8);
#pragma unroll
      for (int j = 0; j < 4; j++){
        pa[kc][j]     = (dva[kc][j] >= 0.1f) ? pv[j]     : (short)0;
        pa[kc][j + 4] = (dvb[kc][j] >= 0.1f) ? pv[j + 4] : (short)0;
      }
    }

    // ---- O += P V : 4 ht x 4 kc ----
#pragma unroll
    for (int ht = 0; ht < 4; ht++){
      int h = ht * 32 + l32;
#pragma unroll
      for (int kc = 0; kc < 4; kc++){
        int slot = kc * 2 + h5;                 // 0..7
        int ph   = (slot ^ h) & 7;
        short8 vf = *(const short8*)((const char*)vls + h * 128 + ph * 16);
        o[ht] = __builtin_amdgcn_mfma_f32_32x32x16_bf16(pa[kc], vf, o[ht], 0, 0, 0);
      }
    }
    __syncthreads();                            // protect kls/vls rewrite
  }

  // ---- l reduce across the 32 key-cols (lanes of each half) ----
  float lrow[16];
#pragma unroll
  for (int r = 0; r < 16; r++){
    float v = lpart[r];
    v += __shfl_xor(v, 1);
    v += __shfl_xor(v, 2);
    v += __shfl_xor(v, 4);
    v += __shfl_xor(v, 8);
    v += __shfl_xor(v, 16);
    lrow[r] = v;
  }

  if (split == 1){
    float* op = out + ((size_t)b * S_ + m0) * H_;
#pragma unroll
    for (int ht = 0; ht < 4; ht++)
#pragma unroll
      for (int r = 0; r < 16; r++){
        int row = (r & 3) + 8 * (r >> 2) + 4 * h5;
        op[(size_t)row * H_ + ht * 32 + l32] = o[ht][r] * KINV / lrow[r];
      }
  } else {
#pragma unroll
    for (int r = 0; r < 16; r++){
      int row = (r & 3) + 8 * (r >> 2) + 4 * h5;
      size_t R = (size_t)b * S_ + m0 + row;
#pragma unroll
      for (int ht = 0; ht < 4; ht++)
        po[((size_t)sp * NR_ + R) * H_ + ht * 32 + l32] = o[ht][r] * KINV;
      if (l32 == 0) pl[(size_t)sp * NR_ + R] = lrow[r];
    }
  }
}

// ---------------------------------------------------------------------------
__global__ void combine(const float* __restrict__ po, const float* __restrict__ pl,
                        float* __restrict__ out, int split){
  int row = blockIdx.x;
  int col = threadIdx.x;
  float num = 0.f, den = 0.f;
  for (int s = 0; s < split; s++){
    num += po[((size_t)s * NR_ + row) * H_ + col];
    den += pl[(size_t)s * NR_ + row];
  }
  out[(size_t)row * H_ + col] = num / den;
}

// ---------------------------------------------------------------------------
extern "C" void kernel_launch(void* const* d_in, const int* in_sizes, int n_in,
                              void* d_out, int out_size, void* d_ws, size_t ws_size,
                              hipStream_t stream){
  const float* x  = (const float*)d_in[0];
  const float* wq = (const float*)d_in[1];
  const float* wk = (const float*)d_in[2];
  const float* wv = (const float*)d_in[3];
  const float* du = (const float*)d_in[4];
  float* out = (float*)d_out;

  const size_t MiB = 1048576;
  char* ws = (char*)d_ws;
  short* qm = (short*)(ws);                      // 4 MiB
  short* km = (short*)(ws + 4 * MiB);            // 4 MiB
  short* vt = (short*)(ws + 8 * MiB);            // 4 MiB
  short* xb = (short*)(ws + 12 * MiB);           // 32 MiB
  short* wt = (short*)(ws + 44 * MiB);           // 768 KiB
  float* pl = (float*)(ws + 45 * MiB);           // split*64 KiB
  float* po = (float*)(ws + 45 * MiB + 524288);  // split*8 MiB

  size_t base  = 45 * MiB + 524288;
  size_t needA = base + 32 * MiB;
  size_t needB = base + 16 * MiB;
  int split = (ws_size >= needA) ? 4 : (ws_size >= needB) ? 2 : 1;

  hipLaunchKernelGGL(prep,     dim3(8576),        dim3(256), 0, stream, x, wq, wk, wv, xb, wt);
  hipLaunchKernelGGL(qkv_gemm, dim3(3, 128),      dim3(256), 0, stream, xb, wt, qm, km, vt);
  hipLaunchKernelGGL(attn,     dim3(128 * split), dim3(256), 0, stream,
                     qm, km, vt, du, po, pl, out, split);
  if (split > 1)
    hipLaunchKernelGGL(combine, dim3(NR_), dim3(H_), 0, stream, po, pl, out, split);
}